// Round 11
// baseline (163.662 us; speedup 1.0000x reference)
//
#include <hip/hip_runtime.h>
#include <cstdio>
#include <cstdint>

// Problem constants
#define BATCH 8
#define CH    512
#define OC3   1536      // 3*CH
#define QKROWS 1024     // Q+K channel rows (bf16)
#define NPIX  4096      // 64*64
#define HEADS 8
#define HDIM  64
#define KDEPTH 512      // GEMM K
#define SCALE 0.125f    // 64^-0.5
#define NSPLIT 16       // split-K factor for QK^T (256 n per split)

typedef __bf16 bf16;
typedef __bf16 bf16x4 __attribute__((ext_vector_type(4)));
typedef __bf16 bf16x8 __attribute__((ext_vector_type(8)));
typedef float  f32x4  __attribute__((ext_vector_type(4)));

#define AS1 __attribute__((address_space(1)))
#define AS3 __attribute__((address_space(3)))

// ---------------------------------------------------------------------------
// fp32 -> bf16 flat convert (weights)
// ---------------------------------------------------------------------------
__global__ __launch_bounds__(256) void convert_bf16_kernel(
    const float* __restrict__ in, bf16* __restrict__ out, int n)
{
    const int i = blockIdx.x * 256 + threadIdx.x;
    if (i < n) out[i] = (bf16)in[i];
}

// ---------------------------------------------------------------------------
// src [b][512][4096] fp32 -> dst [b][4096][512] bf16 (transpose + convert)
// ---------------------------------------------------------------------------
__global__ __launch_bounds__(256) void transpose_convert_kernel(
    const float* __restrict__ src, bf16* __restrict__ dst, size_t src_bstride)
{
    const int b  = blockIdx.z;
    const int n0 = blockIdx.x * 64;
    const int c0 = blockIdx.y * 64;
    __shared__ float tile[64][65];
    const int t = threadIdx.x;
    const float* xp = src + (size_t)b * src_bstride;

    #pragma unroll
    for (int i = 0; i < 4; ++i) {
        const int lin = t + 256 * i;
        const int r   = lin >> 4;
        const int c4  = (lin & 15) * 4;
        const float4 v = *(const float4*)(xp + (size_t)(c0 + r) * 4096 + n0 + c4);
        tile[r][c4 + 0] = v.x; tile[r][c4 + 1] = v.y;
        tile[r][c4 + 2] = v.z; tile[r][c4 + 3] = v.w;
    }
    __syncthreads();

    bf16* op = dst + (size_t)b * 4096 * 512;
    #pragma unroll
    for (int i = 0; i < 2; ++i) {
        const int lin = t + 256 * i;
        const int n   = lin >> 3;
        const int c8  = (lin & 7) * 8;
        bf16x8 v;
        #pragma unroll
        for (int jj = 0; jj < 8; ++jj) v[jj] = (bf16)tile[c8 + jj][n];
        *(bf16x8*)(op + (size_t)(n0 + n) * 512 + c0 + c8) = v;
    }
}

// ---------------------------------------------------------------------------
// NEW: 256x256 counted-vmcnt pipelined MFMA GEMM (T3+T4+T5, 2-phase/K-tile).
// C[b][m][n] = sum_k A[b][m][k] * Bt[b][n][k] + bias[m]
//   qkb != null -> bf16 output; else fp32 C. c_rows = output rows per batch.
// 512 thr = 8 waves (2M x 4N), per-wave 128x64 out, BK=32, ring-4 LDS bufs.
// LDS line = 2 rows x 32 bf16 = 8 x 16B chunks, chunk-XOR slot^(line&7)
// applied on BOTH gload_lds source and ds_read (dest linear, rule #21).
// vmcnt(4) at tile end (never 0 mid-loop): kt+2 prefetch stays in flight.
// ---------------------------------------------------------------------------
__global__ __launch_bounds__(512, 2) void gemm256_kernel(
    const bf16* __restrict__ A, const bf16* __restrict__ Bt,
    const float* __restrict__ bias, float* __restrict__ C,
    bf16* __restrict__ qkb, int c_rows, size_t a_bstride)
{
    const int b  = blockIdx.z;
    const int m0 = blockIdx.y * 256;
    const int n0 = blockIdx.x * 256;
    const bf16* Ap = A  + (size_t)b * a_bstride;
    const bf16* Bp = Bt + (size_t)b * NPIX * KDEPTH;

    // 4 ring buffers x (A 8192 bf16 | B 8192 bf16) = 128 KiB
    __shared__ bf16 lds[65536];

    const int t    = threadIdx.x;
    const int lane = t & 63;
    const int wave = t >> 6;
    const int wm   = wave >> 2;      // 0..1  (M half: 128 rows)
    const int wn   = wave & 3;       // 0..3  (N quarter: 64 cols)
    const int kc   = lane >> 4;      // k-chunk 0..3 within BK=32

    f32x4 acc[8][4];
    const f32x4 zf = {0.f, 0.f, 0.f, 0.f};
    #pragma unroll
    for (int i = 0; i < 8; ++i)
        #pragma unroll
        for (int j = 0; j < 4; ++j) acc[i][j] = zf;

    // stage half of K-tile (2 gload_lds: one A chunk-set, one B chunk-set)
    auto STAGE2 = [&](int ktile, int half) {
        const int cid  = t + 512 * half;    // 0..1023 16B-chunks per matrix
        const int l    = cid >> 3;          // line 0..127 (rows 2l,2l+1)
        const int s    = cid & 7;           // slot in line
        const int v    = s ^ (l & 7);       // inverse swizzle
        const int srow = l * 2 + (v >> 2);  // source row 0..255
        const int skc  = v & 3;             // source k-chunk
        const int k0   = ktile * 32;
        bf16* ldsb = lds + (ktile & 3) * 16384;
        __builtin_amdgcn_global_load_lds(
            (const AS1 void*)(Ap + (size_t)(m0 + srow) * KDEPTH + k0 + skc * 8),
            (AS3 void*)(ldsb + cid * 8), 16, 0, 0);
        __builtin_amdgcn_global_load_lds(
            (const AS1 void*)(Bp + (size_t)(n0 + srow) * KDEPTH + k0 + skc * 8),
            (AS3 void*)(ldsb + 8192 + cid * 8), 16, 0, 0);
    };

    // one phase: ds_read 4 A-frags + 4 B-frags (swizzled), 16 MFMA
    auto PHASE = [&](int ktile, int mh) {
        const bf16* buf = lds + (ktile & 3) * 16384;
        bf16x8 af[4], bfr[4];
        #pragma unroll
        for (int mfl = 0; mfl < 4; ++mfl) {
            const int row = wm * 128 + mh * 64 + mfl * 16 + (lane & 15);
            const int l   = row >> 1;
            const int sl  = (((row & 1) << 2) + kc) ^ (l & 7);
            af[mfl] = *(const bf16x8*)(buf + l * 64 + sl * 8);
        }
        #pragma unroll
        for (int nf = 0; nf < 4; ++nf) {
            const int row = wn * 64 + nf * 16 + (lane & 15);
            const int l   = row >> 1;
            const int sl  = (((row & 1) << 2) + kc) ^ (l & 7);
            bfr[nf] = *(const bf16x8*)(buf + 8192 + l * 64 + sl * 8);
        }
        __builtin_amdgcn_s_setprio(1);
        #pragma unroll
        for (int mfl = 0; mfl < 4; ++mfl)
            #pragma unroll
            for (int nf = 0; nf < 4; ++nf)
                acc[mh * 4 + mfl][nf] = __builtin_amdgcn_mfma_f32_16x16x32_bf16(
                    af[mfl], bfr[nf], acc[mh * 4 + mfl][nf], 0, 0, 0);
        __builtin_amdgcn_s_setprio(0);
    };

    // prologue: stage tiles 0,1 fully; wait tile0 landed (4 newer may fly)
    STAGE2(0, 0); STAGE2(0, 1); STAGE2(1, 0); STAGE2(1, 1);
    asm volatile("s_waitcnt vmcnt(4)" ::: "memory");
    __builtin_amdgcn_s_barrier();

    const int NKT = KDEPTH / 32;   // 16
    for (int kt = 0; kt < NKT; ++kt) {
        if (kt < NKT - 2) STAGE2(kt + 2, 0);
        PHASE(kt, 0);
        __builtin_amdgcn_s_barrier();
        if (kt < NKT - 2) STAGE2(kt + 2, 1);
        PHASE(kt, 1);
        // counted drain: next tile's 4 loads must land; newest 4 may fly
        if (kt < NKT - 2)       asm volatile("s_waitcnt vmcnt(4)" ::: "memory");
        else if (kt == NKT - 2) asm volatile("s_waitcnt vmcnt(0)" ::: "memory");
        __builtin_amdgcn_s_barrier();
    }

    // epilogue
    if (qkb) {
        bf16* Qp = qkb + (size_t)b * c_rows * NPIX;
        #pragma unroll
        for (int mf = 0; mf < 8; ++mf) {
            const int mb = m0 + wm * 128 + mf * 16 + (lane >> 4) * 4;
            #pragma unroll
            for (int r = 0; r < 4; ++r) {
                const int m  = mb + r;
                const float bv = bias[m];
                #pragma unroll
                for (int nf = 0; nf < 4; ++nf) {
                    const int n = n0 + wn * 64 + nf * 16 + (lane & 15);
                    Qp[(size_t)m * NPIX + n] = (bf16)(acc[mf][nf][r] + bv);
                }
            }
        }
    } else {
        float* Cp = C + (size_t)b * c_rows * NPIX;
        #pragma unroll
        for (int mf = 0; mf < 8; ++mf) {
            const int mb = m0 + wm * 128 + mf * 16 + (lane >> 4) * 4;
            #pragma unroll
            for (int r = 0; r < 4; ++r) {
                const int m  = mb + r;
                const float bv = bias[m];
                #pragma unroll
                for (int nf = 0; nf < 4; ++nf) {
                    const int n = n0 + wn * 64 + nf * 16 + (lane & 15);
                    Cp[(size_t)m * NPIX + n] = acc[mf][nf][r] + bv;
                }
            }
        }
    }
}

// ---------------------------------------------------------------------------
// OLD 128x128 GEMM — retained for the V rows only (fused transpose epilogue):
// vt[b][n][m0+..] bf16. 2-phase dbuf + k-chunk XOR swizzle.
// ---------------------------------------------------------------------------
__global__ __launch_bounds__(256) void mfma_gemm_kernel(
    const bf16* __restrict__ A, const bf16* __restrict__ Bt,
    const float* __restrict__ bias, bf16* __restrict__ vt, size_t a_bstride)
{
    const int b  = blockIdx.z;
    const int m0 = blockIdx.y * 128;
    const int n0 = blockIdx.x * 128;
    const bf16* Ap = A  + (size_t)b * a_bstride;
    const bf16* Bp = Bt + (size_t)b * NPIX * KDEPTH;

    __shared__ bf16 smem[16384];

    const int t    = threadIdx.x;
    const int lane = t & 63;
    const int wave = t >> 6;
    const int wr   = wave >> 1, wc = wave & 1;

    f32x4 acc[4][4];
    const f32x4 zf = {0.f, 0.f, 0.f, 0.f};
    #pragma unroll
    for (int i = 0; i < 4; ++i)
        #pragma unroll
        for (int j = 0; j < 4; ++j) acc[i][j] = zf;

    auto STAGE = [&](int p, int k0) {
        #pragma unroll
        for (int i = 0; i < 2; ++i) {
            const int c   = t + 256 * i;
            const int row = c >> 2;
            const int kb  = ((c & 3) ^ ((row >> 1) & 3)) * 8;
            __builtin_amdgcn_global_load_lds(
                (const AS1 void*)(Ap + (size_t)(m0 + row) * KDEPTH + k0 + kb),
                (AS3 void*)(smem + p * 8192 + c * 8), 16, 0, 0);
            __builtin_amdgcn_global_load_lds(
                (const AS1 void*)(Bp + (size_t)(n0 + row) * KDEPTH + k0 + kb),
                (AS3 void*)(smem + p * 8192 + 4096 + c * 8), 16, 0, 0);
        }
    };

    STAGE(0, 0);
    __syncthreads();
    int cur = 0;

    for (int kt = 0; kt < KDEPTH / 32; ++kt) {
        if (kt < KDEPTH / 32 - 1) STAGE(cur ^ 1, (kt + 1) * 32);

        const bf16* AsP = smem + cur * 8192;
        const bf16* BsP = AsP + 4096;
        bf16x8 af[4], bfv[4];
        #pragma unroll
        for (int i = 0; i < 4; ++i) {
            const int ar = wr * 64 + i * 16 + (lane & 15);
            const int ja = (lane >> 4) ^ ((ar >> 1) & 3);
            af[i]  = *(const bf16x8*)(AsP + ar * 32 + ja * 8);
            const int br = wc * 64 + i * 16 + (lane & 15);
            const int jb = (lane >> 4) ^ ((br >> 1) & 3);
            bfv[i] = *(const bf16x8*)(BsP + br * 32 + jb * 8);
        }
        #pragma unroll
        for (int i = 0; i < 4; ++i)
            #pragma unroll
            for (int j = 0; j < 4; ++j)
                acc[i][j] = __builtin_amdgcn_mfma_f32_16x16x32_bf16(
                    af[i], bfv[j], acc[i][j], 0, 0, 0);

        __syncthreads();
        cur ^= 1;
    }

    // fused V epilogue: bf16 + transpose -> vt[b][n][m0 + ...]
    bf16* vb = vt + (size_t)b * NPIX * KDEPTH;
    bf16* tb = smem;
    #pragma unroll
    for (int p = 0; p < 2; ++p) {
        if (wc == p) {
            #pragma unroll
            for (int i = 0; i < 4; ++i) {
                const int ml = wr * 64 + i * 16 + (lane >> 4) * 4;
                #pragma unroll
                for (int j = 0; j < 4; ++j) {
                    const int ns = j * 16 + (lane & 15);
                    bf16x4 pk;
                    #pragma unroll
                    for (int r = 0; r < 4; ++r)
                        pk[r] = (bf16)(acc[i][j][r] + bias[m0 + ml + r]);
                    *(bf16x4*)(tb + ns * 132 + ml) = pk;
                }
            }
        }
        __syncthreads();
        #pragma unroll
        for (int ii = 0; ii < 4; ++ii) {
            const int lin = t + 256 * ii;
            const int row = lin >> 4;
            const int seg = lin & 15;
            const int4 v = *(const int4*)(tb + row * 132 + seg * 8);
            *(int4*)(vb + (size_t)(n0 + p * 64 + row) * KDEPTH + m0 + seg * 8) = v;
        }
        __syncthreads();
    }
}

// ---------------------------------------------------------------------------
// QK^T split-K partial (MFMA): part[bh][s][d][e] = sum_{n in split} q[d,n]k[e,n]
// ---------------------------------------------------------------------------
__global__ __launch_bounds__(256) void qk_partial_kernel(
    const bf16* __restrict__ qk, float* __restrict__ part)
{
    const int s  = blockIdx.x;
    const int bh = blockIdx.y;
    const int b = bh >> 3, h = bh & 7;
    const bf16* qbase = qk + ((size_t)b * QKROWS + h * HDIM) * NPIX;
    const bf16* kbase = qk + ((size_t)b * QKROWS + CH + h * HDIM) * NPIX;

    __shared__ bf16 smem[16384];

    const int t    = threadIdx.x;
    const int lane = t & 63;
    const int wave = t >> 6;

    f32x4 acc[4];
    const f32x4 zf = {0.f, 0.f, 0.f, 0.f};
    #pragma unroll
    for (int j = 0; j < 4; ++j) acc[j] = zf;

    auto STAGE = [&](int p, int n0) {
        #pragma unroll
        for (int i = 0; i < 2; ++i) {
            const int c   = t + 256 * i;
            const int row = c >> 3;
            const int nb  = ((c & 7) ^ (row & 7)) * 8;
            __builtin_amdgcn_global_load_lds(
                (const AS1 void*)(qbase + (size_t)row * NPIX + n0 + nb),
                (AS3 void*)(smem + p * 8192 + c * 8), 16, 0, 0);
            __builtin_amdgcn_global_load_lds(
                (const AS1 void*)(kbase + (size_t)row * NPIX + n0 + nb),
                (AS3 void*)(smem + p * 8192 + 4096 + c * 8), 16, 0, 0);
        }
    };

    STAGE(0, s * 256);
    __syncthreads();
    int cur = 0;

    for (int nc = 0; nc < 4; ++nc) {
        if (nc < 3) STAGE(cur ^ 1, s * 256 + (nc + 1) * 64);

        const bf16* Qs = smem + cur * 8192;
        const bf16* Ks = Qs + 4096;
        #pragma unroll
        for (int ks = 0; ks < 2; ++ks) {
            const int dr = wave * 16 + (lane & 15);
            const int ja = (ks * 4 + (lane >> 4)) ^ (dr & 7);
            const bf16x8 af = *(const bf16x8*)(Qs + dr * 64 + ja * 8);
            #pragma unroll
            for (int j = 0; j < 4; ++j) {
                const int er = j * 16 + (lane & 15);
                const int jb = (ks * 4 + (lane >> 4)) ^ (er & 7);
                const bf16x8 bf_ = *(const bf16x8*)(Ks + er * 64 + jb * 8);
                acc[j] = __builtin_amdgcn_mfma_f32_16x16x32_bf16(af, bf_, acc[j], 0, 0, 0);
            }
        }
        __syncthreads();
        cur ^= 1;
    }

    float* pb = part + (((size_t)bh * NSPLIT + s) * 64) * 64;
    #pragma unroll
    for (int j = 0; j < 4; ++j)
        #pragma unroll
        for (int r = 0; r < 4; ++r)
            pb[(size_t)(wave * 16 + (lane >> 4) * 4 + r) * 64 + j * 16 + (lane & 15)] = acc[j][r];
}

// ---------------------------------------------------------------------------
// Reduce partials + row softmax -> attn[bh][d][e] (fp32)
// ---------------------------------------------------------------------------
__global__ __launch_bounds__(256) void qk_reduce_softmax_kernel(
    const float* __restrict__ part, float* __restrict__ attn)
{
    const int bh = blockIdx.x;
    const int t  = threadIdx.x;
    const int r  = t >> 2;
    const int e0 = (t & 3) * 16;

    float v[16];
    #pragma unroll
    for (int i = 0; i < 16; ++i) v[i] = 0.f;

    const float* pb = part + ((size_t)bh * NSPLIT * 64) * 64 + r * 64 + e0;
    for (int s = 0; s < NSPLIT; ++s) {
        const float* ps = pb + (size_t)s * 4096;
        #pragma unroll
        for (int c4 = 0; c4 < 4; ++c4) {
            const float4 p = *(const float4*)(ps + c4 * 4);
            v[c4 * 4 + 0] += p.x; v[c4 * 4 + 1] += p.y;
            v[c4 * 4 + 2] += p.z; v[c4 * 4 + 3] += p.w;
        }
    }

    float m = -1e30f;
    #pragma unroll
    for (int i = 0; i < 16; ++i) m = fmaxf(m, v[i]);
    m = fmaxf(m, __shfl_xor(m, 1));
    m = fmaxf(m, __shfl_xor(m, 2));

    float sum = 0.f;
    #pragma unroll
    for (int i = 0; i < 16; ++i) {
        v[i] = __expf((v[i] - m) * SCALE);
        sum += v[i];
    }
    sum += __shfl_xor(sum, 1);
    sum += __shfl_xor(sum, 2);
    const float inv = 1.f / sum;

    float* arow = attn + ((size_t)bh * 64 + r) * 64 + e0;
    #pragma unroll
    for (int c4 = 0; c4 < 4; ++c4) {
        float4 o;
        o.x = v[c4 * 4 + 0] * inv; o.y = v[c4 * 4 + 1] * inv;
        o.z = v[c4 * 4 + 2] * inv; o.w = v[c4 * 4 + 3] * inv;
        *(float4*)(arow + c4 * 4) = o;
    }
}

// ---------------------------------------------------------------------------
// attn_mean[b][d][e] = mean_h attn[b][h][d][e]
// ---------------------------------------------------------------------------
__global__ __launch_bounds__(256) void attn_mean_kernel(
    const float* __restrict__ attn, float* __restrict__ om)
{
    const int idx = blockIdx.x * 256 + threadIdx.x;
    const int b = idx >> 12, de = idx & 4095;
    float s = 0.f;
    #pragma unroll
    for (int h = 0; h < 8; ++h)
        s += attn[(((size_t)b * 8 + h) << 12) + de];
    om[idx] = s * 0.125f;
}

// ---------------------------------------------------------------------------
// W'[b][o][h*64+e] = sum_d proj_w[o][h*64+d] * attn[b,h,d,e]   (fp32 -> bf16)
// ---------------------------------------------------------------------------
__global__ __launch_bounds__(256) void wprime_kernel(
    const float* __restrict__ proj_w, const float* __restrict__ attn,
    bf16* __restrict__ wp)
{
    const int o0 = blockIdx.x * 64;
    const int h  = blockIdx.y;
    const int b  = blockIdx.z;

    __shared__ float ws[64][65];
    __shared__ float as_[64][65];

    const int t = threadIdx.x;
    #pragma unroll
    for (int i = 0; i < 4; ++i) {
        const int lin = t + 256 * i;
        const int r   = lin >> 4;
        const int c4  = (lin & 15) * 4;
        const float4 wv = *(const float4*)(proj_w + (size_t)(o0 + r) * CH + h * HDIM + c4);
        ws[r][c4 + 0] = wv.x; ws[r][c4 + 1] = wv.y;
        ws[r][c4 + 2] = wv.z; ws[r][c4 + 3] = wv.w;
        const float4 av = *(const float4*)(attn + (((size_t)(b * 8 + h) * 64) + r) * 64 + c4);
        as_[r][c4 + 0] = av.x; as_[r][c4 + 1] = av.y;
        as_[r][c4 + 2] = av.z; as_[r][c4 + 3] = av.w;
    }
    __syncthreads();

    const int tx = t & 15, ty = t >> 4;
    const int to = ty * 4, te = tx * 4;
    float acc[4][4] = {};
    for (int d = 0; d < 64; ++d) {
        float a[4], bb[4];
        #pragma unroll
        for (int i = 0; i < 4; ++i) a[i]  = ws[to + i][d];
        #pragma unroll
        for (int j = 0; j < 4; ++j) bb[j] = as_[d][te + j];
        #pragma unroll
        for (int i = 0; i < 4; ++i)
            #pragma unroll
            for (int j = 0; j < 4; ++j)
                acc[i][j] = fmaf(a[i], bb[j], acc[i][j]);
    }

    bf16* wb = wp + (size_t)b * CH * CH;
    #pragma unroll
    for (int i = 0; i < 4; ++i)
        #pragma unroll
        for (int j = 0; j < 4; ++j)
            wb[(size_t)(o0 + to + i) * CH + h * HDIM + te + j] = (bf16)acc[i][j];
}

// ---------------------------------------------------------------------------
extern "C" void kernel_launch(void* const* d_in, const int* in_sizes, int n_in,
                              void* d_out, int out_size, void* d_ws, size_t ws_size,
                              hipStream_t stream)
{
    (void)in_sizes; (void)n_in; (void)out_size;
    const float* x      = (const float*)d_in[0];
    const float* qkv_w  = (const float*)d_in[1];
    const float* qkv_b  = (const float*)d_in[2];
    const float* proj_w = (const float*)d_in[3];
    const float* proj_b = (const float*)d_in[4];

    float* out       = (float*)d_out;
    float* attn_mean = out + (size_t)BATCH * CH * NPIX;

    const size_t qk_bytes   = (size_t)BATCH * QKROWS * NPIX * 2;        //  64 MiB (bf16)
    const size_t xt_bytes   = (size_t)BATCH * NPIX * KDEPTH * 2;        //  32 MiB
    const size_t vt_bytes   = (size_t)BATCH * NPIX * KDEPTH * 2;        //  32 MiB
    const size_t wq_bytes   = (size_t)OC3 * KDEPTH * 2;                 // 1.5 MiB
    const size_t attn_bytes = (size_t)BATCH * HEADS * HDIM * HDIM * 4;  //   1 MiB
    const size_t part_bytes = (size_t)BATCH * HEADS * NSPLIT * HDIM * HDIM * 4; // 16 MiB
    const size_t wp_bytes   = (size_t)BATCH * CH * CH * 2;              //   4 MiB
    const size_t need = qk_bytes + xt_bytes + vt_bytes + wq_bytes + attn_bytes + part_bytes + wp_bytes;
    if (ws_size < need) {
        fprintf(stderr, "[kernel_launch] ws_size=%zu < need=%zu — abort\n", ws_size, need);
        fflush(stderr);
        return;
    }

    char* p = (char*)d_ws;
    bf16*  qk     = (bf16*)p;             p += qk_bytes;
    bf16*  xt     = (bf16*)p;             p += xt_bytes;
    bf16*  vt     = (bf16*)p;             p += vt_bytes;
    bf16*  wq_b   = (bf16*)p;             p += wq_bytes;
    float* attn   = (float*)p;            p += attn_bytes;
    float* part   = (float*)p;            p += part_bytes;
    bf16*  wprime = (bf16*)p;

    // 0) QKV weight convert
    convert_bf16_kernel<<<dim3((OC3 * KDEPTH + 255) / 256), 256, 0, stream>>>(
        qkv_w, wq_b, OC3 * KDEPTH);

    // 1) x -> xt (transpose + bf16)
    transpose_convert_kernel<<<dim3(NPIX / 64, KDEPTH / 64, BATCH), 256, 0, stream>>>(
        x, xt, (size_t)CH * NPIX);

    // 2a) Q,K GEMM (new 256^2 pipelined) -> bf16 qk[b][1024][4096]
    gemm256_kernel<<<dim3(NPIX / 256, QKROWS / 256, BATCH), 512, 0, stream>>>(
        wq_b, xt, qkv_b, nullptr, qk, QKROWS, 0);

    // 2b) V GEMM (old 128^2, fused transpose) -> bf16 vt[b][4096][512]
    mfma_gemm_kernel<<<dim3(NPIX / 128, CH / 128, BATCH), 256, 0, stream>>>(
        wq_b + (size_t)QKROWS * KDEPTH, xt, qkv_b + QKROWS, vt, 0);

    // 3) QK^T split-K (MFMA) + softmax
    qk_partial_kernel<<<dim3(NSPLIT, BATCH * HEADS), 256, 0, stream>>>(qk, part);
    qk_reduce_softmax_kernel<<<dim3(BATCH * HEADS), 256, 0, stream>>>(part, attn);

    // 4) attn mean over heads (output 1)
    attn_mean_kernel<<<dim3(BATCH * HDIM * HDIM / 256), 256, 0, stream>>>(attn, attn_mean);

    // 5) W' = proj_w · blockdiag(attn)
    wprime_kernel<<<dim3(CH / 64, HEADS, BATCH), 256, 0, stream>>>(proj_w, attn, wprime);

    // 6) out = W'_b · V_b + proj_b  (new 256^2, fp32 epilogue)
    gemm256_kernel<<<dim3(NPIX / 256, CH / 256, BATCH), 512, 0, stream>>>(
        wprime, vt, proj_b, out, nullptr, CH, (size_t)CH * CH);
}